// Round 13
// baseline (76.103 us; speedup 1.0000x reference)
//
#include <hip/hip_runtime.h>
#include <math.h>

#define EPS 1e-9f

__device__ __forceinline__ int tri_off(int I) { return I * (193 - I) / 2; }  // 96 tiles

// Symmetric tile-pair kernel, rotate-by-4 register scatter.
// Wave t handles unordered tile pair (I<=J); lane l owns I-body l (ax,ay).
// Off-diagonal: step m (0..15) processes J-bodies (l+4m+s)&63 for s=0..3 into
// 4 accumulator pairs G_s, then rotates all G_s by 4 lanes (2 bpermute per
// 4 pairs instead of 2 per pair as in R12; serial chain 16 deep, not 64).
// Final placement: G_s[t] holds J-body (t+s)'s partial -> J-body j total =
// G_0[j] + shfl(G_1, j-1) + shfl(G_2, j-2) + shfl(G_3, j-3).
// Diagonal: gather k=1..63 (rotation never self-pairs) + base-position fold.
__global__ __launch_bounds__(256)
void collide(const float2* __restrict__ cpos,
             const float*  __restrict__ crad,
             const float2* __restrict__ apos,
             const float2* __restrict__ ahalf,
             float* __restrict__ out,
             int Nc) {
    const int lane = threadIdx.x & 63;
    const int w    = threadIdx.x >> 6;
    const int t    = blockIdx.x * 4 + w;          // tile-pair id 0..4655 (uniform)

    // triangular decode t -> (I, J), I <= J  (37249 - 8t exact in f32)
    int I = (int)((193.0f - sqrtf((float)(37249 - 8 * t))) * 0.5f);
    while (tri_off(I + 1) <= t) ++I;
    while (tri_off(I) > t) --I;
    const int J = I + (t - tri_off(I));

    const int tileC  = Nc >> 6;                   // 64 circle tiles
    const bool bodyC = I < tileC;                 // uniform
    const bool partC = J < tileC;                 // uniform (I<=J: partC => bodyC)

    __shared__ float4 Jd[4][128];

    {   // stage J tile (doubled); circle radius pre-halved
        const int j = (J << 6) + lane;
        float4 q;
        if (partC) {
            const float2 c = cpos[j];
            q = make_float4(c.x, c.y, 0.5f * crad[j], 0.0f);
        } else {
            const float2 a = apos[j - Nc];
            const float2 h = ahalf[j - Nc];
            q = make_float4(a.x, a.y, h.x, h.y);
        }
        Jd[w][lane]      = q;
        Jd[w][lane + 64] = q;
    }
    __syncthreads();

    const int i = (I << 6) + lane;
    float4 me;
    if (bodyC) {
        const float2 c = cpos[i];
        me = make_float4(c.x, c.y, 0.5f * crad[i], 0.0f);
    } else {
        const float2 a = apos[i - Nc];
        const float2 h = ahalf[i - Nc];
        me = make_float4(a.x, a.y, h.x, h.y);
    }

    float ax = 0.0f, ay = 0.0f;

    if (I != J) {
        float gx0 = 0.f, gy0 = 0.f, gx1 = 0.f, gy1 = 0.f;
        float gx2 = 0.f, gy2 = 0.f, gx3 = 0.f, gy3 = 0.f;
        const int src4 = (lane + 4) & 63;

        if (partC) {                              // CC (both circle tiles)
            const float px = me.x, py = me.y, rih = me.z;
            #pragma unroll 4
            for (int m = 0; m < 16; ++m) {
                const int base = lane + (m << 2);
                float fx[4], fy[4];
                #pragma unroll
                for (int s = 0; s < 4; ++s) {
                    const float4 q = Jd[w][base + s];
                    const float dx = q.x - px, dy = q.y - py;    // q - p
                    const float d2 = fmaf(dx, dx, dy * dy);
                    const float r  = __builtin_amdgcn_rsqf(d2);
                    const float sc = fmaxf(fmaf(rih + q.z, r, -0.5f), 0.0f);
                    fx[s] = sc * dx; fy[s] = sc * dy;            // force on J body
                    ax -= fx[s]; ay -= fy[s];                    // equal & opposite
                }
                gx0 += fx[0]; gy0 += fy[0]; gx1 += fx[1]; gy1 += fy[1];
                gx2 += fx[2]; gy2 += fy[2]; gx3 += fx[3]; gy3 += fy[3];
                gx0 = __shfl(gx0, src4, 64); gy0 = __shfl(gy0, src4, 64);
                gx1 = __shfl(gx1, src4, 64); gy1 = __shfl(gy1, src4, 64);
                gx2 = __shfl(gx2, src4, 64); gy2 = __shfl(gy2, src4, 64);
                gx3 = __shfl(gx3, src4, 64); gy3 = __shfl(gy3, src4, 64);
            }
        } else if (bodyC) {                       // CB: I circle tile, J box tile
            const float px = me.x, py = me.y, rih = me.z;
            #pragma unroll 4
            for (int m = 0; m < 16; ++m) {
                const int base = lane + (m << 2);
                float fx[4], fy[4];
                #pragma unroll
                for (int s = 0; s < 4; ++s) {
                    const float4 q = Jd[w][base + s];
                    const float rx = q.x - px, ry = q.y - py;    // box - circle
                    const float cx = fminf(fmaxf(rx, -q.z), q.z);
                    const float cy = fminf(fmaxf(ry, -q.w), q.w);
                    const float dx = rx - cx, dy = ry - cy;
                    const float d2 = fmaf(dx, dx, dy * dy);
                    const float r  = __builtin_amdgcn_rsqf(d2);
                    float sc = fmaxf(fmaf(rih, r, -0.5f), 0.0f);
                    sc = (d2 > EPS) ? sc : 0.0f;                 // center-inside-box guard
                    fx[s] = sc * dx; fy[s] = sc * dy;            // force on box
                    ax -= fx[s]; ay -= fy[s];                    // push on circle
                }
                gx0 += fx[0]; gy0 += fy[0]; gx1 += fx[1]; gy1 += fy[1];
                gx2 += fx[2]; gy2 += fy[2]; gx3 += fx[3]; gy3 += fy[3];
                gx0 = __shfl(gx0, src4, 64); gy0 = __shfl(gy0, src4, 64);
                gx1 = __shfl(gx1, src4, 64); gy1 = __shfl(gy1, src4, 64);
                gx2 = __shfl(gx2, src4, 64); gy2 = __shfl(gy2, src4, 64);
                gx3 = __shfl(gx3, src4, 64); gy3 = __shfl(gy3, src4, 64);
            }
        } else {                                  // BB (both box tiles)
            const float bx = me.x, by = me.y, hx = me.z, hy = me.w;
            #pragma unroll 4
            for (int m = 0; m < 16; ++m) {
                const int base = lane + (m << 2);
                float fx[4], fy[4];
                #pragma unroll
                for (int s = 0; s < 4; ++s) {
                    const float4 q = Jd[w][base + s];
                    const float dqx = q.x - bx, dqy = q.y - by;  // q - me
                    const float ovx = (hx + q.z) - fabsf(dqx);
                    const float ovy = (hy + q.w) - fabsf(dqy);
                    const bool hit = fminf(ovx, ovy) > 0.0f;
                    const bool ux  = ovx <= ovy;
                    fx[s] = (hit && ux)  ? copysignf(0.5f * ovx, dqx) : 0.0f;
                    fy[s] = (hit && !ux) ? copysignf(0.5f * ovy, dqy) : 0.0f;
                    ax -= fx[s]; ay -= fy[s];
                }
                gx0 += fx[0]; gy0 += fy[0]; gx1 += fx[1]; gy1 += fy[1];
                gx2 += fx[2]; gy2 += fy[2]; gx3 += fx[3]; gy3 += fy[3];
                gx0 = __shfl(gx0, src4, 64); gy0 = __shfl(gy0, src4, 64);
                gx1 = __shfl(gx1, src4, 64); gy1 = __shfl(gy1, src4, 64);
                gx2 = __shfl(gx2, src4, 64); gy2 = __shfl(gy2, src4, 64);
                gx3 = __shfl(gx3, src4, 64); gy3 = __shfl(gy3, src4, 64);
            }
        }

        // G_s[t] holds J-body (t+s)'s partial -> gather the 4 residues
        float tx = gx0, ty = gy0;
        tx += __shfl(gx1, (lane + 63) & 63, 64);  // G_1[lane-1]
        ty += __shfl(gy1, (lane + 63) & 63, 64);
        tx += __shfl(gx2, (lane + 62) & 63, 64);  // G_2[lane-2]
        ty += __shfl(gy2, (lane + 62) & 63, 64);
        tx += __shfl(gx3, (lane + 61) & 63, 64);  // G_3[lane-3]
        ty += __shfl(gy3, (lane + 61) & 63, 64);
        atomicAdd(&out[(((J << 6) + lane) << 1)],     tx);
        atomicAdd(&out[(((J << 6) + lane) << 1) + 1], ty);
    } else {
        // diagonal: gather k=1..63; fold base position here (unique per body)
        if (bodyC) {                              // CC diag
            const float px = me.x, py = me.y, rih = me.z;
            #pragma unroll 7
            for (int k = 1; k < 64; ++k) {
                const float4 q = Jd[w][lane + k];
                const float dx = px - q.x, dy = py - q.y;        // p - q (I side)
                const float d2 = fmaf(dx, dx, dy * dy);
                const float r  = __builtin_amdgcn_rsqf(d2);
                const float s  = fmaxf(fmaf(rih + q.z, r, -0.5f), 0.0f);
                ax = fmaf(s, dx, ax); ay = fmaf(s, dy, ay);
            }
        } else {                                  // BB diag
            const float bx = me.x, by = me.y, hx = me.z, hy = me.w;
            #pragma unroll 7
            for (int k = 1; k < 64; ++k) {
                const float4 q = Jd[w][lane + k];
                const float dax = bx - q.x, day = by - q.y;
                const float ovx = (hx + q.z) - fabsf(dax);
                const float ovy = (hy + q.w) - fabsf(day);
                const bool hit = fminf(ovx, ovy) > 0.0f;
                const bool ux  = ovx <= ovy;
                ax += (hit && ux)  ? copysignf(0.5f * ovx, dax) : 0.0f;
                ay += (hit && !ux) ? copysignf(0.5f * ovy, day) : 0.0f;
            }
        }
        ax += me.x; ay += me.y;                   // base position
    }

    atomicAdd(&out[(i << 1)],     ax);
    atomicAdd(&out[(i << 1) + 1], ay);
}

extern "C" void kernel_launch(void* const* d_in, const int* in_sizes, int n_in,
                              void* d_out, int out_size, void* d_ws, size_t ws_size,
                              hipStream_t stream) {
    (void)n_in; (void)d_ws; (void)ws_size;

    const float2* cpos  = (const float2*)d_in[0];
    const float*  crad  = (const float*) d_in[1];
    const float2* apos  = (const float2*)d_in[2];
    const float2* ahalf = (const float2*)d_in[3];

    const int Nc = in_sizes[1];       // 4096

    // out accumulates via atomics; zero it (small: ~48 KB)
    hipMemsetAsync(d_out, 0, (size_t)out_size * sizeof(float), stream);

    const int tile_pairs = (96 * 97) / 2;       // 4656
    const int blocks = tile_pairs / 4;          // 1164
    collide<<<blocks, 256, 0, stream>>>(cpos, crad, apos, ahalf, (float*)d_out, Nc);
}